// Round 12
// baseline (285.933 us; speedup 1.0000x reference)
//
#include <hip/hip_runtime.h>
#include <hip/hip_bf16.h>
#include <stdint.h>
#include <stddef.h>

// Causal single-head attention, B=4 S=2048 D=1024. fp32 in/out; bf16 MFMA inside.
// R19: fix Sc packing. R18's sc_dp (256x128, 512thr, 96KB LDS) ran 1 block/CU
// with 288 blocks on 256 CUs -> makespan 2 block-times, half the chip idle.
// Replaced by sc544: pv_dp's proven 128^2 / 4-wave / 64KB / 2-blocks-per-CU
// deep-pipeline shape with R14's verified 544-block triangular decode
// (2.1 jobs per residency slot, near-uniform). Schedule, vmcnt(4) proof,
// fragment formulas identical to pv_dp; only lda/ldb=D, NT=16, decode and
// the bf16*0.03125 epilogue differ.
// qkv_8p / pv_dp / softmax / f2b verbatim R18 (controls).

typedef __hip_bfloat16 bf16;
typedef short short8 __attribute__((ext_vector_type(8)));
typedef short short4v __attribute__((ext_vector_type(4)));
typedef float f32x4 __attribute__((ext_vector_type(4)));

#define MSZ 8192   // B*S
#define DD 1024    // D
#define SS 2048    // S

__global__ __launch_bounds__(256)
void f2b(const float* __restrict__ s, bf16* __restrict__ d, int n) {
  const int i = (blockIdx.x * 256 + threadIdx.x) * 4;
  if (i >= n) return;
  const float4 v = *(const float4*)(s + i);
  bf16 t[4] = {__float2bfloat16(v.x), __float2bfloat16(v.y),
               __float2bfloat16(v.z), __float2bfloat16(v.w)};
  *(short4v*)(d + i) = *(short4v*)t;
}

__global__ __launch_bounds__(256)
void f2b3(const float* __restrict__ a, const float* __restrict__ b,
          const float* __restrict__ c, bf16* __restrict__ d, int n) {
  const float* s = (blockIdx.y == 0) ? a : (blockIdx.y == 1) ? b : c;
  const int i = (blockIdx.x * 256 + threadIdx.x) * 4;
  if (i >= n) return;
  const float4 v = *(const float4*)(s + i);
  bf16 t[4] = {__float2bfloat16(v.x), __float2bfloat16(v.y),
               __float2bfloat16(v.z), __float2bfloat16(v.w)};
  *(short4v*)(d + (size_t)blockIdx.y * n + i) = *(short4v*)t;
}

// ---------------- QKV: 256x128 deep-pipeline (verbatim R17/R18) ----------------
__global__ __launch_bounds__(512, 1)
void qkv_8p(const bf16* __restrict__ A, const bf16* __restrict__ B,
            bf16* __restrict__ C, bf16* __restrict__ C2) {
  __shared__ short8 As[2][2048];
  __shared__ short8 Bs[2][1024];

  const int flat = blockIdx.x;
  const int c = flat & 7, j = flat >> 3;
  const int by = c * 4 + (j & 3), bx = j >> 2;
  const int bm0 = by * 256, bn0 = bx * 128;
  const int tid = threadIdx.x, wave = tid >> 6, lane = tid & 63;
  const int wm = wave >> 1, wn = wave & 1;
  const int l15 = lane & 15, q4 = lane >> 4;
  const int rh = l15 >> 3, r3 = l15 & 7;
  const int sr = lane & 7, sgk = (lane >> 3) & 3, shb = lane >> 5;

  const bf16* apg = A + (size_t)(bm0 + wave * 32 + shb * 8 + sr) * DD + sgk * 8;
  const bf16* bpg = B + (size_t)(bn0 + wave * 16 + shb * 8 + sr) * DD + sgk * 8;

  const int NT = DD / 64;

  auto stage = [&](int t, int ks) {
    const int b = t & 1;
    const size_t ko = (size_t)(t * 64 + ks * 32);
#pragma unroll
    for (int i = 0; i < 2; i++)
      __builtin_amdgcn_global_load_lds(apg + (size_t)(i * 16) * DD + ko,
                                       &As[b][ks * 1024 + wave * 128 + i * 64], 16, 0, 0);
    __builtin_amdgcn_global_load_lds(bpg + ko,
                                     &Bs[b][ks * 512 + wave * 64], 16, 0, 0);
  };

  const int fa = wm * 256 + rh * 32 + q4 * 8 + r3;
  const int fb = wn * 256 + rh * 32 + q4 * 8 + r3;

  f32x4 acc[4][4] = {};

  stage(0, 0);
  stage(0, 1);
  asm volatile("s_waitcnt vmcnt(3)" ::: "memory");
  asm volatile("s_barrier" ::: "memory");

  for (int t = 0; t < NT; ++t) {
    const int b = t & 1;
#pragma unroll
    for (int ks = 0; ks < 2; ++ks) {
      short8 af[4], bfr[4];
#pragma unroll
      for (int i = 0; i < 4; i++) af[i] = As[b][ks * 1024 + fa + i * 64];
#pragma unroll
      for (int jj = 0; jj < 4; jj++) bfr[jj] = Bs[b][ks * 512 + fb + jj * 64];
      if (t + 1 < NT) {
        stage(t + 1, ks);
        asm volatile("s_waitcnt vmcnt(3)" ::: "memory");
      } else {
        asm volatile("s_waitcnt vmcnt(0)" ::: "memory");
      }
      asm volatile("s_barrier" ::: "memory");
      __builtin_amdgcn_s_setprio(1);
#pragma unroll
      for (int i = 0; i < 4; i++)
#pragma unroll
        for (int jj = 0; jj < 4; jj++)
          acc[i][jj] = __builtin_amdgcn_mfma_f32_16x16x32_bf16(af[i], bfr[jj], acc[i][jj], 0, 0, 0);
      __builtin_amdgcn_s_setprio(0);
      asm volatile("s_barrier" ::: "memory");
    }
  }

  if (bx >= 16) {
#pragma unroll
    for (int i = 0; i < 4; i++) {
#pragma unroll
      for (int jj = 0; jj < 4; jj++) {
        const int rowb = bm0 + wm * 64 + i * 16 + q4 * 4;
        const int v = (bn0 - 2048) + wn * 64 + jj * 16 + l15;
        bf16 t4[4] = {__float2bfloat16(acc[i][jj][0]), __float2bfloat16(acc[i][jj][1]),
                      __float2bfloat16(acc[i][jj][2]), __float2bfloat16(acc[i][jj][3])};
        *(short4v*)(C2 + (size_t)v * MSZ + rowb) = *(short4v*)t4;
      }
    }
    return;
  }
  bf16* Cb = C + (bx >= 8 ? (size_t)MSZ * DD : 0);
  const int coff = (bx & 7) * 128;
#pragma unroll
  for (int i = 0; i < 4; i++) {
#pragma unroll
    for (int jj = 0; jj < 4; jj++) {
#pragma unroll
      for (int r = 0; r < 4; r++) {
        const int row = bm0 + wm * 64 + i * 16 + q4 * 4 + r;
        const int col = coff + wn * 64 + jj * 16 + l15;
        Cb[(size_t)row * DD + col] = __float2bfloat16(acc[i][jj][r]);
      }
    }
  }
}

// ---------------- Sc: 128x128 deep-pipeline, 544-block triangular ----------------
// Sc[zb] = (Q[zb] K[zb]^T)/32. pv_dp shape: 4 waves, 64KB LDS, 2 blocks/CU.
// 544 = 8 XCD x 68; XCD pair owns batch; halves split tri range 0..135.
__global__ __launch_bounds__(256, 2)
void sc544(const bf16* __restrict__ Q, const bf16* __restrict__ Kp,
           bf16* __restrict__ Sc) {
  __shared__ short8 As[2][1024];
  __shared__ short8 Bs[2][1024];

  const int flat = blockIdx.x;
  const int c = flat & 7, j = flat >> 3;
  const int zb = c >> 1;
  const int t = (c & 1) * 68 + j;
  int by = (int)((__fsqrt_rn(8.f * (float)t + 1.f) - 1.f) * 0.5f);
  while ((by + 1) * (by + 2) / 2 <= t) by++;
  while (by * (by + 1) / 2 > t) by--;
  const int bx = t - by * (by + 1) / 2;

  const int bm0 = by * 128, bn0 = bx * 128;
  const int tid = threadIdx.x, wave = tid >> 6, lane = tid & 63;
  const int wm = wave >> 1, wn = wave & 1;
  const int l15 = lane & 15, q4 = lane >> 4;
  const int rh = l15 >> 3, r3 = l15 & 7;
  const int sr = lane & 7, sgk = (lane >> 3) & 3, shb = lane >> 5;

  const bf16* Az = Q + (size_t)zb * SS * DD;
  const bf16* Bz = Kp + (size_t)zb * SS * DD;
  const bf16* apg = Az + (size_t)(bm0 + wave * 32 + shb * 8 + sr) * DD + sgk * 8;
  const bf16* bpg = Bz + (size_t)(bn0 + wave * 32 + shb * 8 + sr) * DD + sgk * 8;

  const int NT = DD / 64;  // 16

  auto stage = [&](int tt, int ks) {
    const int b = tt & 1;
    const size_t ko = (size_t)(tt * 64 + ks * 32);
#pragma unroll
    for (int i = 0; i < 2; i++) {
      __builtin_amdgcn_global_load_lds(apg + (size_t)(i * 16) * DD + ko,
                                       &As[b][ks * 512 + wave * 128 + i * 64], 16, 0, 0);
      __builtin_amdgcn_global_load_lds(bpg + (size_t)(i * 16) * DD + ko,
                                       &Bs[b][ks * 512 + wave * 128 + i * 64], 16, 0, 0);
    }
  };

  const int fa = wm * 256 + rh * 32 + q4 * 8 + r3;
  const int fb = wn * 256 + rh * 32 + q4 * 8 + r3;

  f32x4 acc[4][4] = {};

  stage(0, 0);
  stage(0, 1);
  asm volatile("s_waitcnt vmcnt(4)" ::: "memory");
  asm volatile("s_barrier" ::: "memory");

  for (int tt = 0; tt < NT; ++tt) {
    const int b = tt & 1;
#pragma unroll
    for (int ks = 0; ks < 2; ++ks) {
      short8 af[4], bfr[4];
#pragma unroll
      for (int i = 0; i < 4; i++) af[i] = As[b][ks * 512 + fa + i * 64];
#pragma unroll
      for (int jj = 0; jj < 4; jj++) bfr[jj] = Bs[b][ks * 512 + fb + jj * 64];
      if (tt + 1 < NT) {
        stage(tt + 1, ks);
        asm volatile("s_waitcnt vmcnt(4)" ::: "memory");
      } else {
        asm volatile("s_waitcnt vmcnt(0)" ::: "memory");
      }
      asm volatile("s_barrier" ::: "memory");
      __builtin_amdgcn_s_setprio(1);
#pragma unroll
      for (int i = 0; i < 4; i++)
#pragma unroll
        for (int jj = 0; jj < 4; jj++)
          acc[i][jj] = __builtin_amdgcn_mfma_f32_16x16x32_bf16(af[i], bfr[jj], acc[i][jj], 0, 0, 0);
      __builtin_amdgcn_s_setprio(0);
      asm volatile("s_barrier" ::: "memory");
    }
  }

  bf16* Cz = Sc + (size_t)zb * SS * SS;
#pragma unroll
  for (int i = 0; i < 4; i++) {
#pragma unroll
    for (int jj = 0; jj < 4; jj++) {
#pragma unroll
      for (int r = 0; r < 4; r++) {
        const int row = bm0 + wm * 64 + i * 16 + q4 * 4 + r;
        const int col = bn0 + wn * 64 + jj * 16 + l15;
        Cz[(size_t)row * SS + col] = __float2bfloat16(acc[i][jj][r] * 0.03125f);
      }
    }
  }
}

// ---------------- PV: 128x128 deep-pipeline (verbatim R18) ----------------
__global__ __launch_bounds__(256, 2)
void pv_dp(const bf16* __restrict__ P, const bf16* __restrict__ VT,
           float* __restrict__ out) {
  __shared__ short8 As[2][1024];
  __shared__ short8 Bs[2][1024];

  const int flat = blockIdx.x;
  const int c = flat & 7, j = flat >> 3;
  const int zb = c >> 1;
  const int bx = j & 7;
  const int by = 2 * (7 - (j >> 3)) + (c & 1);

  const int bm0 = by * 128, bn0 = bx * 128;
  const int tid = threadIdx.x, wave = tid >> 6, lane = tid & 63;
  const int wm = wave >> 1, wn = wave & 1;
  const int l15 = lane & 15, q4 = lane >> 4;
  const int rh = l15 >> 3, r3 = l15 & 7;
  const int sr = lane & 7, sgk = (lane >> 3) & 3, shb = lane >> 5;

  const bf16* Az = P + (size_t)zb * SS * SS;
  const bf16* Bz = VT + (size_t)zb * SS;
  const bf16* apg = Az + (size_t)(bm0 + wave * 32 + shb * 8 + sr) * SS + sgk * 8;
  const bf16* bpg = Bz + (size_t)(bn0 + wave * 32 + shb * 8 + sr) * MSZ + sgk * 8;

  const int Ke = min(SS, (by + 1) * 128);
  const int NT = Ke >> 6;

  auto stage = [&](int t, int ks) {
    const int b = t & 1;
    const size_t ko = (size_t)(t * 64 + ks * 32);
#pragma unroll
    for (int i = 0; i < 2; i++) {
      __builtin_amdgcn_global_load_lds(apg + (size_t)(i * 16) * SS + ko,
                                       &As[b][ks * 512 + wave * 128 + i * 64], 16, 0, 0);
      __builtin_amdgcn_global_load_lds(bpg + (size_t)(i * 16) * MSZ + ko,
                                       &Bs[b][ks * 512 + wave * 128 + i * 64], 16, 0, 0);
    }
  };

  const int fa = wm * 256 + rh * 32 + q4 * 8 + r3;
  const int fb = wn * 256 + rh * 32 + q4 * 8 + r3;

  f32x4 acc[4][4] = {};

  stage(0, 0);
  stage(0, 1);
  asm volatile("s_waitcnt vmcnt(4)" ::: "memory");
  asm volatile("s_barrier" ::: "memory");

  for (int t = 0; t < NT; ++t) {
    const int b = t & 1;
#pragma unroll
    for (int ks = 0; ks < 2; ++ks) {
      short8 af[4], bfr[4];
#pragma unroll
      for (int i = 0; i < 4; i++) af[i] = As[b][ks * 512 + fa + i * 64];
#pragma unroll
      for (int jj = 0; jj < 4; jj++) bfr[jj] = Bs[b][ks * 512 + fb + jj * 64];
      if (t + 1 < NT) {
        stage(t + 1, ks);
        asm volatile("s_waitcnt vmcnt(4)" ::: "memory");
      } else {
        asm volatile("s_waitcnt vmcnt(0)" ::: "memory");
      }
      asm volatile("s_barrier" ::: "memory");
      __builtin_amdgcn_s_setprio(1);
#pragma unroll
      for (int i = 0; i < 4; i++)
#pragma unroll
        for (int jj = 0; jj < 4; jj++)
          acc[i][jj] = __builtin_amdgcn_mfma_f32_16x16x32_bf16(af[i], bfr[jj], acc[i][jj], 0, 0, 0);
      __builtin_amdgcn_s_setprio(0);
      asm volatile("s_barrier" ::: "memory");
    }
  }

  float* Cz = out + (size_t)zb * SS * DD;
#pragma unroll
  for (int i = 0; i < 4; i++) {
#pragma unroll
    for (int jj = 0; jj < 4; jj++) {
#pragma unroll
      for (int r = 0; r < 4; r++) {
        const int row = bm0 + wm * 64 + i * 16 + q4 * 4 + r;
        const int col = bn0 + wn * 64 + jj * 16 + l15;
        Cz[(size_t)row * DD + col] = acc[i][jj][r];
      }
    }
  }
}

// Single-pass register softmax over the causal prefix (verbatim R14).
__global__ __launch_bounds__(256)
void softmax_rows(const bf16* __restrict__ Sc, bf16* __restrict__ P, int S) {
  const int q = blockIdx.x, b = blockIdx.y;
  const short8* srow = (const short8*)(Sc + ((size_t)b * S + q) * S);
  short8* prow = (short8*)(P + ((size_t)b * S + q) * S);
  const int len = q + 1;
  const int tid = threadIdx.x;
  const int wave = tid >> 6, lane = tid & 63;
  __shared__ float red[10];

  const short8 raw = srow[tid];
  float v[8];
#pragma unroll
  for (int j = 0; j < 8; j++) {
    const int k = tid * 8 + j;
    const float f = __bfloat162float(((const bf16*)&raw)[j]);
    v[j] = (k < len) ? f : -1e30f;
  }

  float m = v[0];
#pragma unroll
  for (int j = 1; j < 8; j++) m = fmaxf(m, v[j]);
#pragma unroll
  for (int o = 32; o; o >>= 1) m = fmaxf(m, __shfl_down(m, o));
  if (lane == 0) red[wave] = m;
  __syncthreads();
  if (tid == 0) red[8] = fmaxf(fmaxf(red[0], red[1]), fmaxf(red[2], red[3]));
  __syncthreads();
  const float M = red[8];

  float e[8], s = 0.f;
#pragma unroll
  for (int j = 0; j < 8; j++) { e[j] = __expf(v[j] - M); s += e[j]; }
#pragma unroll
  for (int o = 32; o; o >>= 1) s += __shfl_down(s, o);
  if (lane == 0) red[4 + wave] = s;
  __syncthreads();
  if (tid == 0) red[9] = red[4] + red[5] + red[6] + red[7];
  __syncthreads();
  const float inv = 1.f / red[9];

  short8 outp;
#pragma unroll
  for (int j = 0; j < 8; j++) {
    const int k = tid * 8 + j;
    ((bf16*)&outp)[j] = __float2bfloat16((k < len) ? e[j] * inv : 0.f);
  }
  prow[tid] = outp;
}

extern "C" void kernel_launch(void* const* d_in, const int* in_sizes, int n_in,
                              void* d_out, int out_size, void* d_ws, size_t ws_size,
                              hipStream_t stream) {
  const float* x  = (const float*)d_in[0];
  const float* Wq = (const float*)d_in[1];
  const float* Wk = (const float*)d_in[2];
  const float* Wv = (const float*)d_in[3];
  float* out = (float*)d_out;

  const int Bb = 4, S = 2048, D = 1024, MS = Bb * S;  // MS = 8192

  // ws layout; P aliases dead xb/W/Q region (consumed before softmax).
  char* ws = (char*)d_ws;
  bf16* xb = (bf16*)ws;                                          // 16.78 MB
  bf16* wb = (bf16*)(ws + (size_t)MS * D * 2);                   // 6.3 MB
  bf16* Q  = (bf16*)(ws + (size_t)MS * D * 2 + 3u * D * D * 2);  // 16.78 MB
  bf16* Kp = Q + (size_t)MS * D;                                 // 16.78 MB (contig after Q)
  bf16* VT = Kp + (size_t)MS * D;                                // 16.78 MB [D,MS]
  bf16* Sc = VT + (size_t)MS * D;                                // 33.55 MB [B,S,S]
  bf16* P  = (bf16*)ws;                                          // aliases xb/W/Q
  (void)Kp;

  dim3 blk(256);

  f2b<<<dim3(MS * D / 4 / 256), blk, 0, stream>>>(x, xb, MS * D);
  f2b3<<<dim3(D * D / 4 / 256, 3), blk, 0, stream>>>(Wq, Wk, Wv, wb, D * D);

  // QKV fused: deep-pipeline 256x128 (768 blocks x 512 thr)
  qkv_8p<<<dim3(768), dim3(512), 0, stream>>>(xb, wb, Q, VT);
  // Sc = (Q K^T)/32: deep-pipeline 128^2, 544 blocks, 2 blocks/CU
  sc544<<<dim3(544), blk, 0, stream>>>(Q, Kp, Sc);
  // P = row-softmax(Sc)
  softmax_rows<<<dim3(S, Bb), blk, 0, stream>>>(Sc, P, S);
  // out = P @ V: deep-pipeline (512 blocks x 256 thr)
  pv_dp<<<dim3(512), blk, 0, stream>>>(P, VT, out);
}